// Round 2
// baseline (18992.053 us; speedup 1.0000x reference)
//
#include <hip/hip_runtime.h>
#include <math.h>

#define NEG10K -10000.0f
// K=12 tags, START=10, STOP=11, B=64, T=1024, V=50000, D=256, Hh=256, 4Hh=1024

// ---------------- workspace layout (float offsets), total ~12.6 MB ----------------
static const size_t OFF_WT_IH = 0;                  // [2][256][1024]  Wih^T per dir
static const size_t OFF_WT_HH = 524288;             // [2][256][1024]  Whh^T per dir
static const size_t OFF_BIAS  = 1048576;            // [2][1024]       bih+bhh
static const size_t OFF_WTAGD = 1050624;            // [2][16][256]    Wtag halves, k-padded to 16
static const size_t OFF_BTAG  = 1058816;            // [16]
static const size_t OFF_FEATS = 1058832;            // [2][64][1024][16] per-dir partial feats
static const size_t WS_FLOATS = OFF_FEATS + 2097152;

__device__ __forceinline__ float sigf(float x) { return 1.0f / (1.0f + expf(-x)); }

// ---------------- weight transposes: [1024][256] -> [256][1024] ----------------
__global__ __launch_bounds__(256) void k_transpose(
    const float* __restrict__ wih_f, const float* __restrict__ wih_b,
    const float* __restrict__ whh_f, const float* __restrict__ whh_b,
    float* __restrict__ ws) {
  __shared__ float tile[32][33];
  int z = blockIdx.z;
  const float* src = (z == 0) ? wih_f : (z == 1) ? wih_b : (z == 2) ? whh_f : whh_b;
  float* dst = ws + ((z < 2) ? (OFF_WT_IH + (size_t)z * 262144)
                             : (OFF_WT_HH + (size_t)(z - 2) * 262144));
  int r0 = blockIdx.y * 32;  // over 1024 rows of src
  int c0 = blockIdx.x * 32;  // over 256 cols of src
  int tid = threadIdx.x;
  int c = tid & 31, rg = tid >> 5;
#pragma unroll
  for (int i = 0; i < 4; ++i) {
    int r = rg * 4 + i;
    tile[r][c] = src[(size_t)(r0 + r) * 256 + c0 + c];
  }
  __syncthreads();
  int r2 = tid & 31, cg = tid >> 5;
#pragma unroll
  for (int i = 0; i < 4; ++i) {
    int ccv = cg * 4 + i;
    dst[(size_t)(c0 + ccv) * 1024 + r0 + r2] = tile[r2][ccv];
  }
}

// ---------------- small prep: bias combine, Wtag halves (pad K->16), btag pad ----------------
__global__ __launch_bounds__(256) void k_prep_small(
    const float* __restrict__ bih_f, const float* __restrict__ bhh_f,
    const float* __restrict__ bih_b, const float* __restrict__ bhh_b,
    const float* __restrict__ wtag, const float* __restrict__ btag,
    float* __restrict__ ws) {
  int i = blockIdx.x * 256 + threadIdx.x;
  if (i < 2048) {
    int d = i >> 10, n = i & 1023;
    ws[OFF_BIAS + i] = d ? (bih_b[n] + bhh_b[n]) : (bih_f[n] + bhh_f[n]);
  } else if (i < 2048 + 8192) {
    int r = i - 2048;
    int d = r >> 12, rem = r & 4095;
    int k = rem >> 8, j = rem & 255;  // Wtag half d: rows k<12 real, 12..15 zero
    ws[OFF_WTAGD + r] = (k < 12) ? wtag[(size_t)k * 512 + d * 256 + j] : 0.0f;
  } else if (i < 2048 + 8192 + 16) {
    int kk = i - 10240;
    ws[OFF_BTAG + kk] = (kk < 12) ? btag[kk] : 0.0f;
  }
}

// ---------------- fused LSTM + tag-head: 64 WGs = (32 batch-pairs) x (2 dirs) ----------------
#define FMA4(A, W, S) { A.x = fmaf(W.x, S, A.x); A.y = fmaf(W.y, S, A.y); \
                        A.z = fmaf(W.z, S, A.z); A.w = fmaf(W.w, S, A.w); }
__global__ __launch_bounds__(256) void k_lstm(
    const float* __restrict__ ws_c, const int* __restrict__ sentence,
    const float* __restrict__ emb, const float* __restrict__ h0p,
    const float* __restrict__ c0p, const int* __restrict__ seq_lens,
    float* __restrict__ ws_mut) {
  int d = blockIdx.x & 1;          // round-robin XCD dispatch -> one dir per XCD parity
  int pr = blockIdx.x >> 1;
  int b0 = pr * 2, b1 = b0 + 1;
  const float* Wih = ws_c + OFF_WT_IH + (size_t)d * 262144;  // [256][1024]
  const float* Whh = ws_c + OFF_WT_HH + (size_t)d * 262144;  // [256][1024]

  __shared__ float h_s[2][256];
  __shared__ float x_s[2][2][256];        // [buf][batch][256]
  __shared__ float z_s[2][1024];
  __shared__ int   sent_s[2][1024];
  __shared__ float wt_s[16][260];         // Wtag half for this dir, padded stride
  __shared__ float pfp_s[2][16][8];

  int tid = threadIdx.x;
  int len0 = seq_lens[b0], len1 = seq_lens[b1];

  for (int i = tid; i < 2048; i += 256)
    sent_s[i >> 10][i & 1023] = sentence[(size_t)(b0 + (i >> 10)) * 1024 + (i & 1023)];
  for (int i = tid; i < 4096; i += 256) {
    int k = i >> 8, j = i & 255;
    wt_s[k][j] = ws_c[OFF_WTAGD + (size_t)d * 4096 + i];
  }
  h_s[0][tid] = h0p[((size_t)d * 64 + b0) * 256 + tid];
  h_s[1][tid] = h0p[((size_t)d * 64 + b1) * 256 + tid];
  float cc0 = c0p[((size_t)d * 64 + b0) * 256 + tid];
  float cc1 = c0p[((size_t)d * 64 + b1) * 256 + tid];
  int c4 = tid * 4;
  float4 bias_v = *(const float4*)(ws_c + OFF_BIAS + (size_t)d * 1024 + c4);
  __syncthreads();  // sent_s ready before prologue gather

  // prologue: gather x for first step into buffer 0
  int t0 = d ? 1023 : 0;
  if (tid < 128) {
    int bb = tid >> 6, l = tid & 63;
    int row = sent_s[bb][t0];
    float4 v = *(const float4*)(emb + (size_t)row * 256 + l * 4);
    *(float4*)&x_s[0][bb][l * 4] = v;
  }
  __syncthreads();

  float* featsD = ws_mut + OFF_FEATS + (size_t)d * 1048576;

  for (int s = 0; s < 1024; ++s) {
    int t = d ? (1023 - s) : s;
    int cur = s & 1, nxt = cur ^ 1;
    // issue prefetch of next step's x rows (consumed in phase B)
    float4 pf = {0, 0, 0, 0};
    if (tid < 128) {
      int sn = (s < 1023) ? (s + 1) : 1023;
      int tn = d ? (1023 - sn) : sn;
      int bb = tid >> 6, l = tid & 63;
      int row = sent_s[bb][tn];
      pf = *(const float4*)(emb + (size_t)row * 256 + l * 4);
    }
    // ---- phase A: z = bias + x@Wih^T + h@Whh^T for 4 cols x 2 batches ----
    float4 a0 = bias_v, a1 = bias_v;
#pragma unroll 4
    for (int k = 0; k < 256; k += 4) {
      float4 xv0 = *(const float4*)&x_s[cur][0][k];
      float4 xv1 = *(const float4*)&x_s[cur][1][k];
      float4 hv0 = *(const float4*)&h_s[0][k];
      float4 hv1 = *(const float4*)&h_s[1][k];
      const float* wi = Wih + (size_t)k * 1024 + c4;
      const float* wh = Whh + (size_t)k * 1024 + c4;
      float4 wi0 = *(const float4*)(wi);
      float4 wi1 = *(const float4*)(wi + 1024);
      float4 wi2 = *(const float4*)(wi + 2048);
      float4 wi3 = *(const float4*)(wi + 3072);
      float4 wh0 = *(const float4*)(wh);
      float4 wh1 = *(const float4*)(wh + 1024);
      float4 wh2 = *(const float4*)(wh + 2048);
      float4 wh3 = *(const float4*)(wh + 3072);
      FMA4(a0, wi0, xv0.x); FMA4(a0, wi1, xv0.y); FMA4(a0, wi2, xv0.z); FMA4(a0, wi3, xv0.w);
      FMA4(a0, wh0, hv0.x); FMA4(a0, wh1, hv0.y); FMA4(a0, wh2, hv0.z); FMA4(a0, wh3, hv0.w);
      FMA4(a1, wi0, xv1.x); FMA4(a1, wi1, xv1.y); FMA4(a1, wi2, xv1.z); FMA4(a1, wi3, xv1.w);
      FMA4(a1, wh0, hv1.x); FMA4(a1, wh1, hv1.y); FMA4(a1, wh2, hv1.z); FMA4(a1, wh3, hv1.w);
    }
    *(float4*)&z_s[0][c4] = a0;
    *(float4*)&z_s[1][c4] = a1;
    __syncthreads();  // S1
    // ---- phase B: gates for hidden unit tid, both batches; stash next x ----
    {
      float iv = z_s[0][tid], fv = z_s[0][tid + 256];
      float gv = z_s[0][tid + 512], ov = z_s[0][tid + 768];
      float cn = sigf(fv) * cc0 + sigf(iv) * tanhf(gv);
      float hn = sigf(ov) * tanhf(cn);
      bool m = t < len0;
      cc0 = m ? cn : cc0;
      h_s[0][tid] = m ? hn : h_s[0][tid];
    }
    {
      float iv = z_s[1][tid], fv = z_s[1][tid + 256];
      float gv = z_s[1][tid + 512], ov = z_s[1][tid + 768];
      float cn = sigf(fv) * cc1 + sigf(iv) * tanhf(gv);
      float hn = sigf(ov) * tanhf(cn);
      bool m = t < len1;
      cc1 = m ? cn : cc1;
      h_s[1][tid] = m ? hn : h_s[1][tid];
    }
    if (tid < 128) {
      int bb = tid >> 6, l = tid & 63;
      *(float4*)&x_s[nxt][bb][l * 4] = pf;
    }
    __syncthreads();  // S2
    // ---- phase C: partial tag-head  pf[k] = sum_j h[j] * Wtag_half[k][j] ----
    {
      int b2 = tid >> 7, r = tid & 127;
      int ks = r >> 3, jg = r & 7;
      const float* hv = &h_s[b2][jg * 32];
      const float* wv = &wt_s[ks][jg * 32];
      float p = 0.0f;
#pragma unroll
      for (int i = 0; i < 32; ++i) p = fmaf(hv[i], wv[i], p);
      pfp_s[b2][ks][jg] = p;
    }
    __syncthreads();  // S3
    // ---- phase D: reduce + store per-dir feats ----
    if (tid < 32) {
      int b = tid >> 4, k = tid & 15;
      float sum = 0.0f;
#pragma unroll
      for (int i = 0; i < 8; ++i) sum += pfp_s[b][k][i];
      featsD[(size_t)(b0 + b) * 16384 + (size_t)t * 16 + k] = sum;
    }
  }
}

// ---------------- Viterbi + backtrace, one wave per batch element ----------------
__global__ __launch_bounds__(64) void k_viterbi(const float* __restrict__ ws_c,
                                                const float* __restrict__ trans,
                                                const int* __restrict__ seq_lens,
                                                float* __restrict__ out) {
  __shared__ char bp_s[1024][12];
  int b = blockIdx.x, lane = threadIdx.x;
  int len = seq_lens[b];
  float trow[12];
#pragma unroll
  for (int p = 0; p < 12; ++p) trow[p] = (lane < 12) ? trans[lane * 12 + p] : 0.0f;
  float tb = (lane < 16) ? ws_c[OFF_BTAG + lane] : 0.0f;
  float fv = (lane == 10) ? 0.0f : NEG10K;  // START=10
  const float* ff = ws_c + OFF_FEATS + (size_t)b * 16384;
  const float* fb = ws_c + OFF_FEATS + 1048576 + (size_t)b * 16384;
  for (int t = 0; t < 1024; ++t) {
    float ft = (lane < 16) ? (ff[t * 16 + lane] + fb[t * 16 + lane] + tb) : 0.0f;
    float best = -3.0e38f; int arg = 0;
#pragma unroll
    for (int p = 0; p < 12; ++p) {
      float s = __shfl(fv, p) + trow[p];
      if (s > best) { best = s; arg = p; }  // strict >: first-max like jnp.argmax
    }
    bool m = t < len;
    if (m) fv = best + ft;
    if (lane < 12) bp_s[t][lane] = (char)(m ? arg : lane);
  }
  float term = (lane < 12) ? fv + trans[132 + lane] : -3.0e38f;  // STOP row = 11
  float bestv = -3.0e38f; int bestp = 0;
#pragma unroll
  for (int p = 0; p < 12; ++p) {
    float v = __shfl(term, p);
    if (v > bestv) { bestv = v; bestp = p; }
  }
  __syncthreads();
  if (lane == 0) {
    out[b] = bestv;
    int tag = bestp;
    float* po = out + 64 + (size_t)b * 1024;
    for (int t = 1023; t >= 0; --t) {
      po[t] = (t < len) ? (float)tag : 0.0f;
      tag = bp_s[t][tag];
    }
  }
}

extern "C" void kernel_launch(void* const* d_in, const int* in_sizes, int n_in,
                              void* d_out, int out_size, void* d_ws, size_t ws_size,
                              hipStream_t stream) {
  (void)in_sizes; (void)n_in; (void)out_size;
  const int*   sentence = (const int*)d_in[0];
  const int*   seq_lens = (const int*)d_in[1];
  const float* emb      = (const float*)d_in[2];
  const float* wih_f    = (const float*)d_in[3];
  const float* whh_f    = (const float*)d_in[4];
  const float* bih_f    = (const float*)d_in[5];
  const float* bhh_f    = (const float*)d_in[6];
  const float* wih_b    = (const float*)d_in[7];
  const float* whh_b    = (const float*)d_in[8];
  const float* bih_b    = (const float*)d_in[9];
  const float* bhh_b    = (const float*)d_in[10];
  const float* wtag     = (const float*)d_in[11];
  const float* btag     = (const float*)d_in[12];
  const float* trans    = (const float*)d_in[13];
  const float* h0p      = (const float*)d_in[14];
  const float* c0p      = (const float*)d_in[15];
  float* ws  = (float*)d_ws;
  float* out = (float*)d_out;
  if (ws_size < WS_FLOATS * sizeof(float)) return;  // ~12.6 MB scratch

  k_transpose<<<dim3(8, 32, 4), 256, 0, stream>>>(wih_f, wih_b, whh_f, whh_b, ws);
  k_prep_small<<<41, 256, 0, stream>>>(bih_f, bhh_f, bih_b, bhh_b, wtag, btag, ws);
  k_lstm<<<64, 256, 0, stream>>>(ws, sentence, emb, h0p, c0p, seq_lens, ws);
  k_viterbi<<<64, 64, 0, stream>>>(ws, trans, seq_lens, out);
}